// Round 1
// baseline (119.763 us; speedup 1.0000x reference)
//
#include <hip/hip_runtime.h>

#define MD   4
#define B_   4
#define C_   128
#define H_   128
#define W_   256
#define ND   9            // 2*MD+1 displacements per axis
#define CC   4            // channels staged per chunk
#define NW   9            // waves per block, one per dy
#define XPT  4            // x pixels per thread
#define LROW (W_ + 2*MD)  // 264 floats per staged row (4-float zero halos)

typedef float float4v __attribute__((ext_vector_type(4)));

__global__ __launch_bounds__(NW * 64, 4)
void corr_kernel(const float* __restrict__ t1,
                 const float* __restrict__ t2,
                 float* __restrict__ out) {
    __shared__ float t2s[CC][ND][LROW];   // 4*9*264*4 = 38016 B

    const int tid  = threadIdx.x;
    const int lane = tid & 63;
    const int w    = tid >> 6;       // wave id == dy
    const int y    = blockIdx.x;     // 0..127
    const int b    = blockIdx.y;     // 0..3
    const int x0   = lane * XPT;     // 0..252

    // Zero the x-halos once (never overwritten; pad region is always 0).
    for (int s = tid; s < CC * ND; s += NW * 64) {
        int c = s / ND, r = s % ND;
        #pragma unroll
        for (int k = 0; k < MD; ++k) {
            t2s[c][r][k]            = 0.0f;
            t2s[c][r][W_ + MD + k]  = 0.0f;
        }
    }

    float acc[ND][XPT];
    #pragma unroll
    for (int dx = 0; dx < ND; ++dx)
        #pragma unroll
        for (int j = 0; j < XPT; ++j) acc[dx][j] = 0.0f;

    const float* t1base = t1 + ((size_t)(b * C_) * H_ + y) * W_ + x0;

    for (int c0 = 0; c0 < C_; c0 += CC) {
        // ---- stage CC channels x 9 rows into LDS ----
        // 36 row-slots; wave w takes slots [w*4, w*4+4)
        #pragma unroll
        for (int i = 0; i < (CC * ND) / NW; ++i) {
            const int s  = w * ((CC * ND) / NW) + i;
            const int c  = s / ND;
            const int r  = s % ND;
            const int yy = y + r - MD;                  // wave-uniform
            if (0 <= yy && yy < H_) {
                const float* src =
                    t2 + (((size_t)(b * C_ + c0 + c) * H_ + yy) * W_) + lane * 4;
                __builtin_amdgcn_global_load_lds(
                    (const __attribute__((address_space(1))) unsigned int*)src,
                    (__attribute__((address_space(3))) unsigned int*)&t2s[c][r][MD],
                    16, 0, 0);
            } else {
                float4v z = {0.0f, 0.0f, 0.0f, 0.0f};
                *(float4v*)&t2s[c][r][MD + lane * 4] = z;
            }
        }
        __syncthreads();

        // ---- compute: this wave's dy == w ----
        #pragma unroll
        for (int cc = 0; cc < CC; ++cc) {
            const float4v t1v =
                *(const float4v*)(t1base + (size_t)(c0 + cc) * H_ * W_);
            const float* row = &t2s[cc][w][x0];   // window base: idx x0 .. x0+11
            float win[XPT + 2 * MD];
            *(float4v*)&win[0] = *(const float4v*)&row[0];
            *(float4v*)&win[4] = *(const float4v*)&row[4];
            *(float4v*)&win[8] = *(const float4v*)&row[8];
            #pragma unroll
            for (int dx = 0; dx < ND; ++dx)
                #pragma unroll
                for (int j = 0; j < XPT; ++j)
                    acc[dx][j] += t1v[j] * win[dx + j];
        }
        __syncthreads();
    }

    const float scale = 1.0f / (float)C_;
    #pragma unroll
    for (int dx = 0; dx < ND; ++dx) {
        float4v o;
        #pragma unroll
        for (int j = 0; j < XPT; ++j) o[j] = acc[dx][j] * scale;
        const size_t oidx =
            (((size_t)(b * ND * ND) + w * ND + dx) * H_ + y) * W_ + x0;
        *(float4v*)&out[oidx] = o;
    }
}

extern "C" void kernel_launch(void* const* d_in, const int* in_sizes, int n_in,
                              void* d_out, int out_size, void* d_ws, size_t ws_size,
                              hipStream_t stream) {
    const float* t1 = (const float*)d_in[0];
    const float* t2 = (const float*)d_in[1];
    float* out      = (float*)d_out;
    dim3 grid(H_, B_);
    corr_kernel<<<grid, NW * 64, 0, stream>>>(t1, t2, out);
}